// Round 1
// baseline (105.585 us; speedup 1.0000x reference)
//
#include <hip/hip_runtime.h>

// 3D Haar IDWT:
//   out[n,c,2d+dd,2h+hh,2w+ww] = (1/sqrt(8)) * sum_b s(b1,dd)*s(b2,hh)*s(b3,ww) * band_b[n,c,d,h,w]
// where s(L,p)=+1, s(H,0)=+1, s(H,1)=-1. Band letters: (D-axis, H-axis, W-axis).
// Subband dims: N=2, C=64, D=H=W=32. Output: (2, 128, 64, 64, 64) fp32
// (channels 0..63 = reconstruction, 64..127 = feature_map copy).

#define IDWT_SCALE 0.35355339059327373f  // (1/sqrt(2))^3

__device__ __forceinline__ float2 f2add(float2 a, float2 b) {
    return make_float2(a.x + b.x, a.y + b.y);
}
__device__ __forceinline__ float2 f2sub(float2 a, float2 b) {
    return make_float2(a.x - b.x, a.y - b.y);
}

// One thread handles 2 consecutive w positions (a float2 per band) and
// produces 16 output elements = 4 x float4 stores (contiguous in output-w).
__global__ __launch_bounds__(256) void idwt3d_kernel(
    const float* __restrict__ pLLL, const float* __restrict__ pLLH,
    const float* __restrict__ pLHL, const float* __restrict__ pLHH,
    const float* __restrict__ pHLL, const float* __restrict__ pHLH,
    const float* __restrict__ pHHL, const float* __restrict__ pHHH,
    float* __restrict__ out)
{
    // total threads = NC * D * H * (W/2) = 128 * 32 * 32 * 16 = 2,097,152
    const unsigned t = blockIdx.x * 256u + threadIdx.x;
    const unsigned w2 = t & 15u;          // which pair of w (w = 2*w2, 2*w2+1)
    const unsigned h  = (t >> 4) & 31u;
    const unsigned d  = (t >> 9) & 31u;
    const unsigned nc = t >> 14;          // 0..127  (n = nc>>6, c = nc&63)

    const unsigned in_off = (nc << 15) + (d << 10) + (h << 5) + (w2 << 1);

    const float2 lll = *(const float2*)(pLLL + in_off);
    const float2 llh = *(const float2*)(pLLH + in_off);
    const float2 lhl = *(const float2*)(pLHL + in_off);
    const float2 lhh = *(const float2*)(pLHH + in_off);
    const float2 hll = *(const float2*)(pHLL + in_off);
    const float2 hlh = *(const float2*)(pHLH + in_off);
    const float2 hhl = *(const float2*)(pHHL + in_off);
    const float2 hhh = *(const float2*)(pHHH + in_off);

    // Stage 1: combine along W (third letter). Index = ww parity.
    const float2 LL0 = f2add(lll, llh), LL1 = f2sub(lll, llh);
    const float2 LH0 = f2add(lhl, lhh), LH1 = f2sub(lhl, lhh);
    const float2 HL0 = f2add(hll, hlh), HL1 = f2sub(hll, hlh);
    const float2 HH0 = f2add(hhl, hhh), HH1 = f2sub(hhl, hhh);

    // Stage 2: combine along H (second letter). L{hh}{ww}, H{hh}{ww}.
    const float2 L00 = f2add(LL0, LH0), L10 = f2sub(LL0, LH0);
    const float2 L01 = f2add(LL1, LH1), L11 = f2sub(LL1, LH1);
    const float2 H00 = f2add(HL0, HH0), H10 = f2sub(HL0, HH0);
    const float2 H01 = f2add(HL1, HH1), H11 = f2sub(HL1, HH1);

    // Output addressing: out[n, c, od, oh, ow], dims (2,128,64,64,64).
    // base(n,c) = n*2^25 + c*2^18 ; od*4096 + oh*64 + ow ; ow = 4*w2 .. 4*w2+3
    const unsigned out_base = ((nc >> 6) << 25) + ((nc & 63u) << 18)
                            + ((d << 1) << 12) + ((h << 1) << 6) + (w2 << 2);

    // Per (dd,hh): float4 = {Oww0.x, Oww1.x, Oww0.y, Oww1.y} * scale
    // (x = even source w -> ow 4w2,4w2+1 ; y = odd source w -> ow 4w2+2,4w2+3)
    {   // dd=0, hh=0
        const float2 a = f2add(L00, H00), b = f2add(L01, H01);
        *(float4*)(out + out_base) =
            make_float4(a.x * IDWT_SCALE, b.x * IDWT_SCALE,
                        a.y * IDWT_SCALE, b.y * IDWT_SCALE);
    }
    {   // dd=0, hh=1
        const float2 a = f2add(L10, H10), b = f2add(L11, H11);
        *(float4*)(out + out_base + 64) =
            make_float4(a.x * IDWT_SCALE, b.x * IDWT_SCALE,
                        a.y * IDWT_SCALE, b.y * IDWT_SCALE);
    }
    {   // dd=1, hh=0
        const float2 a = f2sub(L00, H00), b = f2sub(L01, H01);
        *(float4*)(out + out_base + 4096) =
            make_float4(a.x * IDWT_SCALE, b.x * IDWT_SCALE,
                        a.y * IDWT_SCALE, b.y * IDWT_SCALE);
    }
    {   // dd=1, hh=1
        const float2 a = f2sub(L10, H10), b = f2sub(L11, H11);
        *(float4*)(out + out_base + 4096 + 64) =
            make_float4(a.x * IDWT_SCALE, b.x * IDWT_SCALE,
                        a.y * IDWT_SCALE, b.y * IDWT_SCALE);
    }
}

// Copy feature_map (2,64,64,64,64) into output channels 64..127.
// In float4 units: src4 = n*2^22 + r ; dst4 = src4 + (n+1)*2^22.
__global__ __launch_bounds__(256) void copy_fm_kernel(
    const float4* __restrict__ src, float4* __restrict__ dst)
{
    const unsigned i = blockIdx.x * 256u + threadIdx.x;  // 8,388,608 total (exact)
    const unsigned n = i >> 22;
    dst[i + ((n + 1u) << 22)] = src[i];
}

extern "C" void kernel_launch(void* const* d_in, const int* in_sizes, int n_in,
                              void* d_out, int out_size, void* d_ws, size_t ws_size,
                              hipStream_t stream) {
    const float* LLL = (const float*)d_in[0];
    const float* LLH = (const float*)d_in[1];
    const float* LHL = (const float*)d_in[2];
    const float* LHH = (const float*)d_in[3];
    const float* HLL = (const float*)d_in[4];
    const float* HLH = (const float*)d_in[5];
    const float* HHL = (const float*)d_in[6];
    const float* HHH = (const float*)d_in[7];
    const float* fm  = (const float*)d_in[8];
    float* out = (float*)d_out;

    // IDWT: 128*32*32*16 threads
    idwt3d_kernel<<<8192, 256, 0, stream>>>(LLL, LLH, LHL, LHH,
                                            HLL, HLH, HHL, HHH, out);
    // feature_map copy: 33,554,432 floats / 4 per thread
    copy_fm_kernel<<<32768, 256, 0, stream>>>((const float4*)fm, (float4*)out);
}

// Round 2
// 94.689 us; speedup vs baseline: 1.1151x; 1.1151x over previous
//
#include <hip/hip_runtime.h>

// 3D Haar IDWT fused with channel-concat copy.
//   out[n,c,2d+dd,2h+hh,2w+ww] = (1/sqrt(8)) * sum_b s(b1,dd)*s(b2,hh)*s(b3,ww) * band_b[n,c,d,h,w]
// s(L,p)=+1, s(H,0)=+1, s(H,1)=-1. Band letters order: (D, H, W).
// Subbands: (2,64,32,32,32) fp32. feature_map: (2,64,64,64,64) fp32.
// Output: (2,128,64,64,64) fp32; channels 0..63 = reconstruction, 64..127 = fm.

#define IDWT_SCALE 0.35355339059327373f  // (1/sqrt(2))^3

typedef float f32x4 __attribute__((ext_vector_type(4)));

#define COPY_BLOCKS 32768u   // 32768*256 float4 = 2^25 float4 = 128 MiB fm
#define IDWT_BLOCKS 4096u    // 128*32*32*8 threads, float4 (4 w) per band/lane

__global__ __launch_bounds__(256) void idwt_concat_fused(
    const float* __restrict__ pLLL, const float* __restrict__ pLLH,
    const float* __restrict__ pLHL, const float* __restrict__ pLHH,
    const float* __restrict__ pHLL, const float* __restrict__ pHLH,
    const float* __restrict__ pHHL, const float* __restrict__ pHHH,
    const f32x4* __restrict__ fm, float* __restrict__ out)
{
    const unsigned b = blockIdx.x;

    if (b < COPY_BLOCKS) {
        // ---- feature_map copy: channels 64..127 ----
        // float4 index i: src layout (2,64,64,64,64) -> n = i>>22.
        // dst float4 index = i + (n+1)*2^22  (skips 64 output channels per n).
        const unsigned i = b * 256u + threadIdx.x;
        const unsigned n = i >> 22;
        const f32x4 v = fm[i];
        __builtin_nontemporal_store(v, (f32x4*)out + (i + ((n + 1u) << 22)));
        return;
    }

    // ---- IDWT: one thread = 4 consecutive source w -> 32 output elems ----
    const unsigned t  = (b - COPY_BLOCKS) * 256u + threadIdx.x;
    const unsigned w4 = t & 7u;           // source w = 4*w4 .. 4*w4+3
    const unsigned h  = (t >> 3) & 31u;
    const unsigned d  = (t >> 8) & 31u;
    const unsigned nc = t >> 13;          // 0..127 (n = nc>>6, c = nc&63)

    const unsigned in_off = (nc << 15) + (d << 10) + (h << 5) + (w4 << 2);

    const f32x4 lll = *(const f32x4*)(pLLL + in_off);
    const f32x4 llh = *(const f32x4*)(pLLH + in_off);
    const f32x4 lhl = *(const f32x4*)(pLHL + in_off);
    const f32x4 lhh = *(const f32x4*)(pLHH + in_off);
    const f32x4 hll = *(const f32x4*)(pHLL + in_off);
    const f32x4 hlh = *(const f32x4*)(pHLH + in_off);
    const f32x4 hhl = *(const f32x4*)(pHHL + in_off);
    const f32x4 hhh = *(const f32x4*)(pHHH + in_off);

    // Stage 1: W butterfly (third letter). Suffix = ww parity.
    const f32x4 LL0 = lll + llh, LL1 = lll - llh;
    const f32x4 LH0 = lhl + lhh, LH1 = lhl - lhh;
    const f32x4 HL0 = hll + hlh, HL1 = hll - hlh;
    const f32x4 HH0 = hhl + hhh, HH1 = hhl - hhh;

    // Stage 2: H butterfly (second letter). L{hh}{ww}, H{hh}{ww}.
    const f32x4 L00 = LL0 + LH0, L10 = LL0 - LH0;
    const f32x4 L01 = LL1 + LH1, L11 = LL1 - LH1;
    const f32x4 H00 = HL0 + HH0, H10 = HL0 - HH0;
    const f32x4 H01 = HL1 + HH1, H11 = HL1 - HH1;

    // Output: (2,128,64,64,64). base = n*2^25 + c*2^18 + 2d*4096 + 2h*64 + 8*w4
    const unsigned out_base = ((nc >> 6) << 25) + ((nc & 63u) << 18)
                            + (d << 13) + (h << 7) + (w4 << 3);

    // Per (dd,hh): A0 = ww0 vec, A1 = ww1 vec over the 4 source w.
    // Interleaved output: {A0.x,A1.x,A0.y,A1.y}, {A0.z,A1.z,A0.w,A1.w}.
#define EMIT(A0, A1, OFS)                                                     \
    {                                                                         \
        const f32x4 o0 = {(A0).x * IDWT_SCALE, (A1).x * IDWT_SCALE,           \
                          (A0).y * IDWT_SCALE, (A1).y * IDWT_SCALE};          \
        const f32x4 o1 = {(A0).z * IDWT_SCALE, (A1).z * IDWT_SCALE,           \
                          (A0).w * IDWT_SCALE, (A1).w * IDWT_SCALE};          \
        __builtin_nontemporal_store(o0, (f32x4*)(out + out_base + (OFS)));    \
        __builtin_nontemporal_store(o1, (f32x4*)(out + out_base + (OFS) + 4));\
    }

    {   // dd=0, hh=0
        const f32x4 A0 = L00 + H00, A1 = L01 + H01;
        EMIT(A0, A1, 0)
    }
    {   // dd=0, hh=1
        const f32x4 A0 = L10 + H10, A1 = L11 + H11;
        EMIT(A0, A1, 64)
    }
    {   // dd=1, hh=0
        const f32x4 A0 = L00 - H00, A1 = L01 - H01;
        EMIT(A0, A1, 4096)
    }
    {   // dd=1, hh=1
        const f32x4 A0 = L10 - H10, A1 = L11 - H11;
        EMIT(A0, A1, 4096 + 64)
    }
#undef EMIT
}

extern "C" void kernel_launch(void* const* d_in, const int* in_sizes, int n_in,
                              void* d_out, int out_size, void* d_ws, size_t ws_size,
                              hipStream_t stream) {
    const float* LLL = (const float*)d_in[0];
    const float* LLH = (const float*)d_in[1];
    const float* LHL = (const float*)d_in[2];
    const float* LHH = (const float*)d_in[3];
    const float* HLL = (const float*)d_in[4];
    const float* HLH = (const float*)d_in[5];
    const float* HHL = (const float*)d_in[6];
    const float* HHH = (const float*)d_in[7];
    const f32x4* fm  = (const f32x4*)d_in[8];
    float* out = (float*)d_out;

    idwt_concat_fused<<<COPY_BLOCKS + IDWT_BLOCKS, 256, 0, stream>>>(
        LLL, LLH, LHL, LHH, HLL, HLH, HHL, HHH, fm, out);
}

// Round 3
// 79.555 us; speedup vs baseline: 1.3272x; 1.1902x over previous
//
#include <hip/hip_runtime.h>

// 3D Haar IDWT fused with channel-concat copy — single dispatch.
//   out[n,c,2d+dd,2h+hh,2w+ww] = (1/sqrt(8)) * sum_b s(b1,dd)*s(b2,hh)*s(b3,ww) * band_b[n,c,d,h,w]
// s(L,p)=+1, s(H,0)=+1, s(H,1)=-1. Band letter order: (D, H, W).
// Subbands: (2,64,32,32,32) fp32. feature_map: (2,64,64,64,64) fp32.
// Output: (2,128,64,64,64) fp32; ch 0..63 = reconstruction, 64..127 = fm.
//
// Store-density note (R2 post-mortem): every 16B store below is contiguous
// across lanes (w2 = lane&15 -> ow = 4*w2..4*w2+3), so nt stores emit full
// 64B lines. The R2 float4-load variant had 32B-strided stores -> ~35%
// write amplification at HBM (WRITE_SIZE 310MB vs 268MB ideal).

#define IDWT_SCALE 0.35355339059327373f  // (1/sqrt(2))^3

typedef float f32x4 __attribute__((ext_vector_type(4)));

#define IDWT_BLOCKS 8192u    // 128*32*32*16 threads, float2 per band per lane
#define COPY_BLOCKS 32768u   // 2^25 float4 = 128 MiB fm

__device__ __forceinline__ float2 f2add(float2 a, float2 b) {
    return make_float2(a.x + b.x, a.y + b.y);
}
__device__ __forceinline__ float2 f2sub(float2 a, float2 b) {
    return make_float2(a.x - b.x, a.y - b.y);
}

__global__ __launch_bounds__(256) void idwt_concat_fused(
    const float* __restrict__ pLLL, const float* __restrict__ pLLH,
    const float* __restrict__ pLHL, const float* __restrict__ pLHH,
    const float* __restrict__ pHLL, const float* __restrict__ pHLH,
    const float* __restrict__ pHHL, const float* __restrict__ pHHH,
    const f32x4* __restrict__ fm, float* __restrict__ out)
{
    const unsigned b = blockIdx.x;

    if (b >= IDWT_BLOCKS) {
        // ---- feature_map copy: channels 64..127 ----
        // float4 index i; src layout (2,64,64,64,64) -> n = i>>22.
        // dst float4 index = i + (n+1)*2^22 (skip 64 output channels per n).
        const unsigned i = (b - IDWT_BLOCKS) * 256u + threadIdx.x;
        const unsigned n = i >> 22;
        const f32x4 v = fm[i];
        __builtin_nontemporal_store(v, (f32x4*)out + (i + ((n + 1u) << 22)));
        return;
    }

    // ---- IDWT: one thread = 2 consecutive source w -> 16 output elems ----
    const unsigned t  = b * 256u + threadIdx.x;
    const unsigned w2 = t & 15u;          // source w = 2*w2, 2*w2+1
    const unsigned h  = (t >> 4) & 31u;
    const unsigned d  = (t >> 9) & 31u;
    const unsigned nc = t >> 14;          // 0..127 (n = nc>>6, c = nc&63)

    const unsigned in_off = (nc << 15) + (d << 10) + (h << 5) + (w2 << 1);

    const float2 lll = *(const float2*)(pLLL + in_off);
    const float2 llh = *(const float2*)(pLLH + in_off);
    const float2 lhl = *(const float2*)(pLHL + in_off);
    const float2 lhh = *(const float2*)(pLHH + in_off);
    const float2 hll = *(const float2*)(pHLL + in_off);
    const float2 hlh = *(const float2*)(pHLH + in_off);
    const float2 hhl = *(const float2*)(pHHL + in_off);
    const float2 hhh = *(const float2*)(pHHH + in_off);

    // Stage 1: W butterfly (third letter). Suffix = ww parity.
    const float2 LL0 = f2add(lll, llh), LL1 = f2sub(lll, llh);
    const float2 LH0 = f2add(lhl, lhh), LH1 = f2sub(lhl, lhh);
    const float2 HL0 = f2add(hll, hlh), HL1 = f2sub(hll, hlh);
    const float2 HH0 = f2add(hhl, hhh), HH1 = f2sub(hhl, hhh);

    // Stage 2: H butterfly (second letter). L{hh}{ww}, H{hh}{ww}.
    const float2 L00 = f2add(LL0, LH0), L10 = f2sub(LL0, LH0);
    const float2 L01 = f2add(LL1, LH1), L11 = f2sub(LL1, LH1);
    const float2 H00 = f2add(HL0, HH0), H10 = f2sub(HL0, HH0);
    const float2 H01 = f2add(HL1, HH1), H11 = f2sub(HL1, HH1);

    // Output: (2,128,64,64,64). base = n*2^25 + c*2^18 + 2d*4096 + 2h*64 + 4*w2
    const unsigned out_base = ((nc >> 6) << 25) + ((nc & 63u) << 18)
                            + (d << 13) + (h << 7) + (w2 << 2);

    // Per (dd,hh): float4 = {Oww0.x, Oww1.x, Oww0.y, Oww1.y} * scale
    // (x = even source w -> ow 4w2,4w2+1 ; y = odd -> ow 4w2+2,4w2+3)
#define EMIT(A0, A1, OFS)                                                     \
    {                                                                         \
        const f32x4 o = {(A0).x * IDWT_SCALE, (A1).x * IDWT_SCALE,            \
                         (A0).y * IDWT_SCALE, (A1).y * IDWT_SCALE};           \
        __builtin_nontemporal_store(o, (f32x4*)(out + out_base + (OFS)));     \
    }

    {   // dd=0, hh=0
        const float2 a = f2add(L00, H00), c = f2add(L01, H01);
        EMIT(a, c, 0)
    }
    {   // dd=0, hh=1
        const float2 a = f2add(L10, H10), c = f2add(L11, H11);
        EMIT(a, c, 64)
    }
    {   // dd=1, hh=0
        const float2 a = f2sub(L00, H00), c = f2sub(L01, H01);
        EMIT(a, c, 4096)
    }
    {   // dd=1, hh=1
        const float2 a = f2sub(L10, H10), c = f2sub(L11, H11);
        EMIT(a, c, 4096 + 64)
    }
#undef EMIT
}

extern "C" void kernel_launch(void* const* d_in, const int* in_sizes, int n_in,
                              void* d_out, int out_size, void* d_ws, size_t ws_size,
                              hipStream_t stream) {
    const float* LLL = (const float*)d_in[0];
    const float* LLH = (const float*)d_in[1];
    const float* LHL = (const float*)d_in[2];
    const float* LHH = (const float*)d_in[3];
    const float* HLL = (const float*)d_in[4];
    const float* HLH = (const float*)d_in[5];
    const float* HHL = (const float*)d_in[6];
    const float* HHH = (const float*)d_in[7];
    const f32x4* fm  = (const f32x4*)d_in[8];
    float* out = (float*)d_out;

    idwt_concat_fused<<<IDWT_BLOCKS + COPY_BLOCKS, 256, 0, stream>>>(
        LLL, LLH, LHL, LHH, HLL, HLH, HHL, HHH, fm, out);
}